// Round 2
// 624.102 us; speedup vs baseline: 1.0451x; 1.0451x over previous
//
#include <hip/hip_runtime.h>
#include <cstddef>

typedef unsigned short ushort_t;
typedef unsigned int uint32;

typedef __bf16   bf16x8 __attribute__((ext_vector_type(8)));
typedef float    f32x16 __attribute__((ext_vector_type(16)));
typedef float    f32x4  __attribute__((ext_vector_type(4)));
typedef ushort_t u16x8  __attribute__((ext_vector_type(8)));
typedef ushort_t u16x4  __attribute__((ext_vector_type(4)));
typedef uint32   u32x4  __attribute__((ext_vector_type(4)));

__device__ __forceinline__ ushort_t f2b(float f) {
  uint32 u = __builtin_bit_cast(uint32, f);
  u += 0x7fff + ((u >> 16) & 1);           // RNE
  return (ushort_t)(u >> 16);
}

__device__ __forceinline__ f32x16 mfma32(bf16x8 a, bf16x8 b, f32x16 c) {
  return __builtin_amdgcn_mfma_f32_32x32x16_bf16(a, b, c, 0, 0, 0);
}

__device__ __forceinline__ void gload_lds16(const void* g, void* l) {
  __builtin_amdgcn_global_load_lds((const __attribute__((address_space(1))) void*)g,
                                   (__attribute__((address_space(3))) void*)l, 16, 0, 0);
}

// ---------------- RoPE table: cos/sin[t][j], t<4096, j<32, fp32 ----------------
__launch_bounds__(256)
__global__ void k_rope_table(float* __restrict__ cosT, float* __restrict__ sinT) {
  int idx = blockIdx.x * 256 + threadIdx.x;   // 4096*32 = 131072
  int t = idx >> 5, j = idx & 31;
  float invf = __expf(-(float)j * (9.210340371976184f / 32.0f));  // 10000^(-j/32)
  float ang = (float)t * invf;
  cosT[idx] = cosf(ang);
  sinT[idx] = sinf(ang);
}

// ---------------- fp32 -> bf16 bulk convert (8 elems/thread) ----------------
__launch_bounds__(256)
__global__ void k_cvt_x(const float* __restrict__ in, ushort_t* __restrict__ out) {
  size_t i = ((size_t)blockIdx.x * 256 + threadIdx.x) * 8;
  f32x4 a = *(const f32x4*)(in + i);
  f32x4 b = *(const f32x4*)(in + i + 4);
  u16x8 v = {f2b(a[0]), f2b(a[1]), f2b(a[2]), f2b(a[3]),
             f2b(b[0]), f2b(b[1]), f2b(b[2]), f2b(b[3])};
  *(u16x8*)(out + i) = v;
}

// ---------------- 64x64-tile transpose + convert: W_f32[K][N] -> Wt_bf16[N][K] ----
__launch_bounds__(256)
__global__ void k_transpose(const float* __restrict__ W, ushort_t* __restrict__ Wt,
                            int K, int N) {
  __shared__ __align__(16) ushort_t tile[64][72];
  int nbx = N >> 6;
  int bx = blockIdx.x % nbx, by = blockIdx.x / nbx;
  int r0 = by << 6, c0 = bx << 6;
  int tid = threadIdx.x;
#pragma unroll
  for (int p = 0; p < 2; p++) {
    int id = p * 256 + tid;
    int r = id >> 3, cs = id & 7;
    const float* src = W + (size_t)(r0 + r) * N + c0 + cs * 8;
    f32x4 a = *(const f32x4*)(src);
    f32x4 b = *(const f32x4*)(src + 4);
    u16x8 v = {f2b(a[0]), f2b(a[1]), f2b(a[2]), f2b(a[3]),
               f2b(b[0]), f2b(b[1]), f2b(b[2]), f2b(b[3])};
    *(u16x8*)&tile[r][cs * 8] = v;
  }
  __syncthreads();
#pragma unroll
  for (int p = 0; p < 2; p++) {
    int id = p * 256 + tid;
    int oc = id >> 3, ocs = id & 7;
    u16x8 v;
#pragma unroll
    for (int j = 0; j < 8; j++) v[j] = tile[ocs * 8 + j][oc];
    *(u16x8*)(Wt + (size_t)(c0 + oc) * K + r0 + ocs * 8) = v;
  }
}

// ---------------- GEMM: C[M][N] = A[M][K] * Bt[N][K]^T, bf16 in, epilogue by MODE
// MODE 0: fp32 store -> outf[M][N]   (final projection to d_out)
// MODE 1: RoPE (q)   -> out0[M][2048] bf16
// MODE 2: KV: cols<512 RoPE K -> kout[M][512]; cols>=512 V^T -> vout[(b*8+g)*64+d][4096]
template <int MODE>
__launch_bounds__(256)
__global__ void k_gemm(const ushort_t* __restrict__ A, const ushort_t* __restrict__ Bt,
                       int M, int N, int K,
                       ushort_t* __restrict__ out0, float* __restrict__ outf,
                       ushort_t* __restrict__ kout, ushort_t* __restrict__ vout,
                       const float* __restrict__ cosT, const float* __restrict__ sinT) {
  __shared__ __align__(16) ushort_t lds[2][2][128 * 32];  // [buf][A/B][row*32]
  const int tid = threadIdx.x;
  const int wave = tid >> 6, lane = tid & 63;
  const int l31 = lane & 31, hf = lane >> 5;
  const int nTn = N >> 7;
  const int bm = blockIdx.x / nTn, bn = blockIdx.x % nTn;
  const int row0 = bm << 7, col0 = bn << 7;

  f32x16 acc[2][2] = {};

  auto stage = [&](int buf, int k0) {
#pragma unroll
    for (int side = 0; side < 2; side++) {
      const ushort_t* src = side ? Bt : A;
      int r0g = side ? col0 : row0;
#pragma unroll
      for (int i = 0; i < 2; i++) {
        int rl = wave * 32 + i * 16 + (lane >> 2);
        int cs = lane & 3;
        const ushort_t* gp = src + (size_t)(r0g + rl) * K + k0 + cs * 8;
        ushort_t* lp = &lds[buf][side][(wave * 32 + i * 16) * 32];
        gload_lds16(gp, lp);
      }
    }
  };

  stage(0, 0);
  __syncthreads();

  const int wm = wave >> 1, wn = wave & 1;
  const int nk = K >> 5;
  for (int kt = 0; kt < nk; kt++) {
    const int buf = kt & 1;
    if (kt + 1 < nk) stage(buf ^ 1, (kt + 1) << 5);
    const ushort_t* la = &lds[buf][0][0];
    const ushort_t* lb = &lds[buf][1][0];
#pragma unroll
    for (int ks = 0; ks < 2; ks++) {
      const int kc = ks * 2 + hf;
      bf16x8 af[2], bg[2];
#pragma unroll
      for (int mi = 0; mi < 2; mi++) {
        int r = wm * 64 + mi * 32 + l31;
        af[mi] = *(const bf16x8*)(la + r * 32 + kc * 8);
      }
#pragma unroll
      for (int ni = 0; ni < 2; ni++) {
        int r = wn * 64 + ni * 32 + l31;
        bg[ni] = *(const bf16x8*)(lb + r * 32 + kc * 8);
      }
#pragma unroll
      for (int mi = 0; mi < 2; mi++)
#pragma unroll
        for (int ni = 0; ni < 2; ni++)
          acc[mi][ni] = mfma32(af[mi], bg[ni], acc[mi][ni]);
    }
    __syncthreads();
  }

  // ---- epilogue ----
  if (MODE == 0) {  // fp32 output
#pragma unroll
    for (int mi = 0; mi < 2; mi++)
#pragma unroll
      for (int ni = 0; ni < 2; ni++) {
        int cg = col0 + wn * 64 + ni * 32 + l31;
#pragma unroll
        for (int r = 0; r < 16; r++) {
          int rg = row0 + wm * 64 + mi * 32 + (r & 3) + 8 * (r >> 2) + 4 * hf;
          outf[(size_t)rg * N + cg] = acc[mi][ni][r];
        }
      }
  } else if (MODE == 1) {  // q + RoPE; wave N-span 64 = one head (frag pair = d / d+32)
    int cg = col0 + wn * 64 + l31;
#pragma unroll
    for (int mi = 0; mi < 2; mi++)
#pragma unroll
      for (int r = 0; r < 16; r++) {
        int rg = row0 + wm * 64 + mi * 32 + (r & 3) + 8 * (r >> 2) + 4 * hf;
        int t = rg & 4095;
        float c = cosT[t * 32 + l31];
        float s = sinT[t * 32 + l31];
        float lo = acc[mi][0][r], hi = acc[mi][1][r];
        out0[(size_t)rg * N + cg]      = f2b(lo * c - hi * s);
        out0[(size_t)rg * N + cg + 32] = f2b(hi * c + lo * s);
      }
  } else {  // MODE 2: KV
    int cb = col0 + wn * 64;
    if (cb < 512) {  // K half: RoPE, store [M][512]
#pragma unroll
      for (int mi = 0; mi < 2; mi++)
#pragma unroll
        for (int r = 0; r < 16; r++) {
          int rg = row0 + wm * 64 + mi * 32 + (r & 3) + 8 * (r >> 2) + 4 * hf;
          int t = rg & 4095;
          float c = cosT[t * 32 + l31];
          float s = sinT[t * 32 + l31];
          float lo = acc[mi][0][r], hi = acc[mi][1][r];
          kout[(size_t)rg * 512 + cb + l31]      = f2b(lo * c - hi * s);
          kout[(size_t)rg * 512 + cb + l31 + 32] = f2b(hi * c + lo * s);
        }
    } else {  // V half: store transposed vout[(b*8+g)*64+d][t], packed 4 t's
#pragma unroll
      for (int mi = 0; mi < 2; mi++)
#pragma unroll
        for (int ni = 0; ni < 2; ni++) {
          int vd = cb + ni * 32 + l31 - 512;
          int g = vd >> 6, d = vd & 63;
#pragma unroll
          for (int g2 = 0; g2 < 4; g2++) {
            int rg = row0 + wm * 64 + mi * 32 + 8 * g2 + 4 * hf;
            int b = rg >> 12, tl = rg & 4095;
            u16x4 pk = {f2b(acc[mi][ni][g2 * 4 + 0]), f2b(acc[mi][ni][g2 * 4 + 1]),
                        f2b(acc[mi][ni][g2 * 4 + 2]), f2b(acc[mi][ni][g2 * 4 + 3])};
            *(u16x4*)(vout + ((size_t)((b * 8 + g) * 64 + d)) * 4096 + tl) = pk;
          }
        }
    }
  }
}

// ---------------- Flash attention, sliding window, GQA ----------------
// Per wave: one (b, head, 32-query tile). S^T = K*Q^T so C-col = query = lane&31;
// online softmax state is per-lane scalar, kept in log2 domain (exp2-based).
// m init = -60 (log2 units) guarantees exp2(NEG*C - m) == 0 for masked entries,
// so no select is needed on the exp path. Defer-max (THR=8): skip o-rescale when
// the running max grows by < 8 log2 units. P exchange via proven shfl_xor path.
// Writes output IN-PLACE over its own q block.
__launch_bounds__(256)
__global__ void k_attn(ushort_t* __restrict__ q, const ushort_t* __restrict__ kk,
                       const ushort_t* __restrict__ vT) {
  const int wave = threadIdx.x >> 6, lane = threadIdx.x & 63;
  const int l31 = lane & 31, hf = lane >> 5;
  const int blk = blockIdx.x;
  const int bh = blk >> 5, qt4 = 31 - (blk & 31);   // long blocks first (tail balance)
  const int b = bh >> 5, hd = bh & 31;
  const int g = hd >> 2;
  const int qt = qt4 * 4 + wave;
  const int t0 = qt << 5;
  const float NEG = -1e30f;
  const float C = 0.18033688011112042f;  // 0.125 * log2(e)

  const ushort_t* qp = q + ((size_t)(b * 4096 + t0 + l31)) * 2048 + hd * 64 + hf * 8;
  bf16x8 qf[4];
#pragma unroll
  for (int ks = 0; ks < 4; ks++) qf[ks] = *(const bf16x8*)(qp + ks * 16);

  const ushort_t* kp = kk + ((size_t)(b * 4096)) * 512 + g * 64 + hf * 8;
  const ushort_t* vp = vT + ((size_t)((b * 8 + g) * 64 + l31)) * 4096 + hf * 8;

  f32x16 o[2] = {};
  float m_i = -60.f, l_i = 0.f;   // m in log2 units
  const int kt0 = (t0 >= 1024) ? ((t0 - 1023) >> 5) : 0;

  for (int kt = kt0; kt <= qt; kt++) {
    const int kb = kt << 5;
    f32x16 sa = {};
#pragma unroll
    for (int ks = 0; ks < 4; ks++) {
      bf16x8 kf = *(const bf16x8*)(kp + (size_t)(kb + l31) * 512 + ks * 16);
      sa = mfma32(kf, qf[ks], sa);
    }
    // hoist V loads: their L2 latency hides under the softmax below
    bf16x8 vf[2][2];
#pragma unroll
    for (int ks = 0; ks < 2; ks++)
#pragma unroll
      for (int mi = 0; mi < 2; mi++)
        vf[ks][mi] = *(const bf16x8*)(vp + (size_t)(mi * 32) * 4096 + kb + ks * 16);

    const bool need_mask = (kt == qt) || (kb < t0 - 992);
    if (need_mask) {
      int base = (t0 + l31) - kb - 4 * hf;  // allowed iff 0 <= base - off < 1024
#pragma unroll
      for (int r = 0; r < 16; r++) {
        int off = (r & 3) + 8 * (r >> 2);
        sa[r] = ((unsigned)(base - off) < 1024u) ? sa[r] : NEG;
      }
    }
    // raw-score max tree (scale once at the end; masked NEG stays monotone)
    float mx = fmaxf(fmaxf(fmaxf(fmaxf(sa[0], sa[1]), fmaxf(sa[2], sa[3])),
                           fmaxf(fmaxf(sa[4], sa[5]), fmaxf(sa[6], sa[7]))),
                     fmaxf(fmaxf(fmaxf(sa[8], sa[9]), fmaxf(sa[10], sa[11])),
                           fmaxf(fmaxf(sa[12], sa[13]), fmaxf(sa[14], sa[15]))));
    mx = fmaxf(mx, __shfl_xor(mx, 32, 64));
    float mx2 = mx * C;
    // defer-max (T13): skip rescale while max grows by < 8 log2-units
    if (!__all(mx2 - m_i <= 8.f)) {
      float m_new = fmaxf(m_i, mx2);
      float alpha = __builtin_amdgcn_exp2f(m_i - m_new);
      l_i *= alpha;
#pragma unroll
      for (int r = 0; r < 16; r++) { o[0][r] *= alpha; o[1][r] *= alpha; }
      m_i = m_new;
    }
    float p[16];
#pragma unroll
    for (int r = 0; r < 16; r++)
      p[r] = __builtin_amdgcn_exp2f(__builtin_fmaf(sa[r], C, -m_i));
    float ps = (((p[0] + p[1]) + (p[2] + p[3])) + ((p[4] + p[5]) + (p[6] + p[7]))) +
               (((p[8] + p[9]) + (p[10] + p[11])) + ((p[12] + p[13]) + (p[14] + p[15])));
    ps += __shfl_xor(ps, 32, 64);
    l_i += ps;

    // pack P (bf16 pairs, keys ascending within pair) — proven shfl_xor exchange
    uint32 u[8];
#pragma unroll
    for (int i = 0; i < 8; i++)
      u[i] = (uint32)f2b(p[2 * i]) | ((uint32)f2b(p[2 * i + 1]) << 16);

#pragma unroll
    for (int ks = 0; ks < 2; ks++) {
      uint32 own0 = hf ? u[4 * ks + 2] : u[4 * ks + 0];
      uint32 own1 = hf ? u[4 * ks + 3] : u[4 * ks + 1];
      uint32 snd0 = hf ? u[4 * ks + 0] : u[4 * ks + 2];
      uint32 snd1 = hf ? u[4 * ks + 1] : u[4 * ks + 3];
      uint32 r0 = (uint32)__shfl_xor((int)snd0, 32, 64);
      uint32 r1 = (uint32)__shfl_xor((int)snd1, 32, 64);
      u32x4 fr;
      fr[0] = hf ? r0 : own0;
      fr[1] = hf ? r1 : own1;
      fr[2] = hf ? own0 : r0;
      fr[3] = hf ? own1 : r1;
      bf16x8 pf = __builtin_bit_cast(bf16x8, fr);
      o[0] = mfma32(vf[ks][0], pf, o[0]);
      o[1] = mfma32(vf[ks][1], pf, o[1]);
    }
  }

  float inv_l = 1.0f / fmaxf(l_i, 1e-20f);
  ushort_t* op = q + ((size_t)(b * 4096 + t0 + l31)) * 2048 + hd * 64;  // in-place
#pragma unroll
  for (int mi = 0; mi < 2; mi++)
#pragma unroll
    for (int g2 = 0; g2 < 4; g2++) {
      int d0 = mi * 32 + 8 * g2 + 4 * hf;
      u16x4 pk = {f2b(o[mi][g2 * 4 + 0] * inv_l), f2b(o[mi][g2 * 4 + 1] * inv_l),
                  f2b(o[mi][g2 * 4 + 2] * inv_l), f2b(o[mi][g2 * 4 + 3] * inv_l)};
      *(u16x4*)(op + d0) = pk;
    }
}

extern "C" void kernel_launch(void* const* d_in, const int* in_sizes, int n_in,
                              void* d_out, int out_size, void* d_ws, size_t ws_size,
                              hipStream_t stream) {
  const float* x   = (const float*)d_in[0];   // fp32 inputs per reference dtypes
  const float* Wq  = (const float*)d_in[1];
  const float* Wkv = (const float*)d_in[2];
  const float* Wo  = (const float*)d_in[3];
  float* outp = (float*)d_out;                // fp32 output per reference dtype

  const int BT = in_sizes[0] / 2048;  // 8192
  const int Bb = BT / 4096;           // 2

  // --- Scratch plan: d_out is 64 MiB fp32; its first 61 MiB host all scratch
  // that is dead before the final GEMM fully overwrites d_out. ws = 40 MiB.
  //   d_out: x_c[0,32M) WqT[32M,40M) WkvT[40M,44M) kbuf[44M,52M)
  //          vbuf[52M,60M) cosT[60M,60.5M) sinT[60.5M,61M)
  //   ws:    qbuf[0,32M) (attn writes in-place)  WoT[32M,40M)
  char* ob = (char*)d_out;
  const size_t MB = 1024 * 1024;
  ushort_t* x_c  = (ushort_t*)(ob);
  ushort_t* WqT  = (ushort_t*)(ob + 32 * MB);
  ushort_t* WkvT = (ushort_t*)(ob + 40 * MB);
  ushort_t* kbuf = (ushort_t*)(ob + 44 * MB);
  ushort_t* vbuf = (ushort_t*)(ob + 52 * MB);
  float*    cosT = (float*)   (ob + 60 * MB);
  float*    sinT = (float*)   (ob + 60 * MB + 512 * 1024);

  char* ws = (char*)d_ws;
  ushort_t* qbuf = (ushort_t*)(ws);
  ushort_t* WoT  = (ushort_t*)(ws + 32 * MB);

  k_rope_table<<<512, 256, 0, stream>>>(cosT, sinT);
  k_cvt_x<<<BT * 2048 / (256 * 8), 256, 0, stream>>>(x, x_c);
  k_transpose<<<32 * 32, 256, 0, stream>>>(Wq, WqT, 2048, 2048);
  k_transpose<<<32 * 16, 256, 0, stream>>>(Wkv, WkvT, 2048, 1024);
  k_transpose<<<32 * 32, 256, 0, stream>>>(Wo, WoT, 2048, 2048);

  k_gemm<1><<<(BT / 128) * (2048 / 128), 256, 0, stream>>>(
      x_c, WqT, BT, 2048, 2048, qbuf, nullptr, nullptr, nullptr, cosT, sinT);
  k_gemm<2><<<(BT / 128) * (1024 / 128), 256, 0, stream>>>(
      x_c, WkvT, BT, 1024, 2048, nullptr, nullptr, kbuf, vbuf, cosT, sinT);

  k_attn<<<Bb * 32 * 32, 256, 0, stream>>>(qbuf, kbuf, vbuf);

  k_gemm<0><<<(BT / 128) * (2048 / 128), 256, 0, stream>>>(
      qbuf, WoT, BT, 2048, 2048, nullptr, outp, nullptr, nullptr, nullptr, nullptr);
}